// Round 1
// baseline (787.597 us; speedup 1.0000x reference)
//
#include <hip/hip_runtime.h>

#define NE    512
#define DIM   64
#define NROWS 131072            // 32*64*64
#define QELEMS (NROWS * DIM)    // 8388608

// ---- output layout (flat f32, reference return order) ----
#define OFF_Q     0
#define OFF_LOSS  8388608
#define OFF_INDS  8388609
#define OFF_NEMB  8519681       // OFF_INDS + 131072
#define OFF_NCS   8552449       // OFF_NEMB + 32768
#define OFF_NEA   8552961       // OFF_NCS  + 512

// ---- workspace layout (floats) ----
#define WS_EMBT   0             // [512][64] transposed codebook
#define WS_ENORM  32768         // [512] ||e||^2 (f32)
#define WS_ESUM   33280         // [64][512] segment-sum accumulator (d*512+e)
#define WS_COUNTS 66048         // [512]
#define WS_LOSS   66560         // [1]
#define WS_TOTAL  66561

// ---------------------------------------------------------------------------
// init: build embT + enorm, zero accumulators (ws is poisoned, re-zero per call)
__global__ __launch_bounds__(256) void k_init(const float* __restrict__ embed,
                                              float* __restrict__ wsf) {
    int tid = blockIdx.x * 256 + threadIdx.x;
    if (tid < 32768) {
        int e = tid >> 6, d = tid & 63;
        wsf[WS_EMBT + tid] = embed[d * NE + e];          // embT[e][d] = embed[d][e]
    } else if (tid < 33280) {
        int e = tid - 32768;
        float s = 0.f;
        for (int d = 0; d < DIM; ++d) {
            float v = embed[d * NE + e];
            s = fmaf(v, v, s);
        }
        wsf[WS_ENORM + e] = s;
    } else if (tid < WS_TOTAL) {
        wsf[tid] = 0.f;
    }
}

// ---------------------------------------------------------------------------
// argmin: one row per thread; fp32 best-2 scan + fp64 re-rank of the top-2.
__global__ __launch_bounds__(256) void k_argmin(const float* __restrict__ in,
                                                const float* __restrict__ wsf,
                                                float* __restrict__ inds_out) {
    const float* __restrict__ embT  = wsf + WS_EMBT;
    const float* __restrict__ enorm = wsf + WS_ENORM;
    int row = blockIdx.x * 256 + threadIdx.x;

    float xv[DIM];
    const float4* xp = reinterpret_cast<const float4*>(in + (size_t)row * DIM);
#pragma unroll
    for (int i = 0; i < DIM / 4; ++i) {
        float4 v = xp[i];
        xv[4*i+0] = v.x; xv[4*i+1] = v.y; xv[4*i+2] = v.z; xv[4*i+3] = v.w;
    }

    float b0 = 3.4e38f, b1 = 3.4e38f;
    int   i0 = 0,       i1 = 0;
    for (int e = 0; e < NE; ++e) {
        const float* __restrict__ ec = embT + e * DIM;   // wave-uniform -> s_load
        float a0 = 0.f, a1 = 0.f, a2 = 0.f, a3 = 0.f;
#pragma unroll
        for (int d = 0; d < DIM; d += 4) {
            a0 = fmaf(xv[d+0], ec[d+0], a0);
            a1 = fmaf(xv[d+1], ec[d+1], a1);
            a2 = fmaf(xv[d+2], ec[d+2], a2);
            a3 = fmaf(xv[d+3], ec[d+3], a3);
        }
        float dist = enorm[e] - 2.0f * ((a0 + a1) + (a2 + a3));
        bool better0 = dist < b0;
        bool better1 = dist < b1;
        b1 = better0 ? b0 : (better1 ? dist : b1);
        i1 = better0 ? i0 : (better1 ? e    : i1);
        b0 = better0 ? dist : b0;
        i0 = better0 ? e    : i0;
    }

    // fp64 re-rank of the two candidates (||x||^2 cancels in the comparison)
    const float* __restrict__ e0 = embT + i0 * DIM;
    const float* __restrict__ e1 = embT + i1 * DIM;
    double s0 = 0.0, s1 = 0.0;
#pragma unroll
    for (int d = 0; d < DIM; ++d) {
        double xd = (double)xv[d];
        double a = (double)e0[d]; s0 += a * (a - 2.0 * xd);
        double b = (double)e1[d]; s1 += b * (b - 2.0 * xd);
    }
    int best = (s1 < s0 || (s1 == s0 && i1 < i0)) ? i1 : i0;
    inds_out[row] = (float)best;
}

// ---------------------------------------------------------------------------
// apply: gather quantized rows (coalesced, d on lanes), loss partial,
// segment-sum atomics. 64 rows per block.
__global__ __launch_bounds__(256) void k_apply(const float* __restrict__ in,
                                               const float* __restrict__ wsf,
                                               float* __restrict__ wsmut,
                                               const float* __restrict__ indsf,
                                               float* __restrict__ qout) {
    const float* __restrict__ embT = wsf + WS_EMBT;
    float* esum   = wsmut + WS_ESUM;
    float* counts = wsmut + WS_COUNTS;
    float* loss   = wsmut + WS_LOSS;

    int wid = threadIdx.x >> 6, lane = threadIdx.x & 63;
    float lsum = 0.f;
    for (int it = 0; it < 16; ++it) {
        int row = blockIdx.x * 64 + it * 4 + wid;        // wave-uniform
        int ind = (int)indsf[row];
        float x = in[(size_t)row * DIM + lane];
        float q = embT[ind * DIM + lane];
        qout[(size_t)row * DIM + lane] = q;
        float df = q - x;
        lsum = fmaf(df, df, lsum);
        atomicAdd(&esum[lane * NE + ind], x);            // 64 distinct addrs / wave
        if (lane == 0) atomicAdd(&counts[ind], 1.0f);
    }
    for (int off = 32; off; off >>= 1) lsum += __shfl_down(lsum, off, 64);
    __shared__ float red[4];
    if (lane == 0) red[wid] = lsum;
    __syncthreads();
    if (threadIdx.x == 0) atomicAdd(loss, red[0] + red[1] + red[2] + red[3]);
}

// ---------------------------------------------------------------------------
// finalize: EMA buffers + normalized codebook + loss scale. One block.
__global__ __launch_bounds__(512) void k_final(const float* __restrict__ wsf,
                                               const float* __restrict__ cs_in,
                                               const float* __restrict__ eavg_in,
                                               float* __restrict__ out) {
    __shared__ float sred[512];
    int t = threadIdx.x;
    float c = 0.99f * cs_in[t] + 0.01f * wsf[WS_COUNTS + t];
    out[OFF_NCS + t] = c;
    sred[t] = c;
    __syncthreads();
    for (int s = 256; s; s >>= 1) {
        if (t < s) sred[t] += sred[t + s];
        __syncthreads();
    }
    float n = sred[0];
    float csv = (c + 1e-5f) / (n + NE * 1e-5f) * n;
    for (int i = t; i < 32768; i += 512) {               // i & 511 == t
        float nea = 0.99f * eavg_in[i] + 0.01f * wsf[WS_ESUM + i];
        out[OFF_NEA + i]  = nea;
        out[OFF_NEMB + i] = nea / csv;
    }
    if (t == 0) out[OFF_LOSS] = wsf[WS_LOSS] * (1.25f / 8388608.0f);
}

// ---------------------------------------------------------------------------
extern "C" void kernel_launch(void* const* d_in, const int* in_sizes, int n_in,
                              void* d_out, int out_size, void* d_ws, size_t ws_size,
                              hipStream_t stream) {
    const float* in    = (const float*)d_in[0];
    const float* embed = (const float*)d_in[1];
    const float* cs    = (const float*)d_in[2];
    const float* eavg  = (const float*)d_in[3];
    float* out = (float*)d_out;
    float* wsf = (float*)d_ws;

    k_init  <<<(WS_TOTAL + 255) / 256, 256, 0, stream>>>(embed, wsf);
    k_argmin<<<NROWS / 256, 256, 0, stream>>>(in, wsf, out + OFF_INDS);
    k_apply <<<NROWS / 64, 256, 0, stream>>>(in, wsf, wsf, out + OFF_INDS, out + OFF_Q);
    k_final <<<1, 512, 0, stream>>>(wsf, cs, eavg, out);
}